// Round 7
// baseline (5890.379 us; speedup 1.0000x reference)
//
#include <hip/hip_runtime.h>

// Problem constants
#define Bz 16
#define Gc 30
#define Hs 24
#define Wd_ 862
#define HW (Hs*Wd_)          // 20688
#define BHW (Bz*HW)          // 331008 = 1293 * 256 exactly
#define PREN 720

__device__ __forceinline__ int imin(int a,int b){return a<b?a:b;}
__device__ __forceinline__ int imax(int a,int b){return a>b?a:b;}

struct Corners { float m00,m01,m10,m11; int i00,i01,i10,i11; };

__device__ __forceinline__ Corners mk_corners(float py, float px){
  float y0f = floorf(py), x0f = floorf(px);
  float wy = py - y0f, wx = px - x0f;
  int y0 = (int)y0f, x0 = (int)x0f;
  int y1 = y0 + 1, x1 = x0 + 1;
  bool y0i = ((unsigned)y0 < (unsigned)Hs);
  bool y1i = ((unsigned)y1 < (unsigned)Hs);
  bool x0i = ((unsigned)x0 < (unsigned)Wd_);
  bool x1i = ((unsigned)x1 < (unsigned)Wd_);
  float w00=(1.f-wy)*(1.f-wx), w01=(1.f-wy)*wx, w10=wy*(1.f-wx), w11=wy*wx;
  Corners c;
  c.m00 = (y0i&&x0i)?w00:0.f; c.m01=(y0i&&x1i)?w01:0.f;
  c.m10 = (y1i&&x0i)?w10:0.f; c.m11=(y1i&&x1i)?w11:0.f;
  int y0c=imin(imax(y0,0),Hs-1), y1c=imin(imax(y1,0),Hs-1);
  int x0c=imin(imax(x0,0),Wd_-1), x1c=imin(imax(x1,0),Wd_-1);
  c.i00=y0c*Wd_+x0c; c.i01=y0c*Wd_+x1c; c.i10=y1c*Wd_+x0c; c.i11=y1c*Wd_+x1c;
  return c;
}

// ---------------- 3x3 conv, LDS row-staged. grid (7, Hs, Bz), block 256 ----
// block = 128 pixels x 2 output-channel halves
template<int OC, int R>
__global__ __launch_bounds__(256) void k_conv3x3s(
    const float* __restrict__ x, const float* __restrict__ Wo,
    const float* __restrict__ bo, float* __restrict__ out)
{
  constexpr int TILE = 128, SW = TILE + 2*R;
  constexpr int OH = (OC + 1) / 2;
  __shared__ float xs[Gc][3][SW];     // <= 47.5 KB
  __shared__ float w_s[9][OC][Gc];    // <= 32.4 KB
  __shared__ float b_s[OC];

  const int b = blockIdx.z, h = blockIdx.y, w0 = blockIdx.x * TILE;

  for (int i = threadIdx.x; i < 9*OC*Gc; i += 256){
    int ki = i/(OC*Gc), rm = i%(OC*Gc); int o = rm/Gc, c = rm%Gc;
    w_s[ki][o][c] = Wo[(o*Gc + c)*9 + ki];
  }
  if (threadIdx.x < OC) b_s[threadIdx.x] = bo[threadIdx.x];

  const float* xb = x + (size_t)b*Gc*HW;
  for (int i = threadIdx.x; i < Gc*3*SW; i += 256){
    int c = i/(3*SW), rm = i%(3*SW); int rr = rm/SW, ww = rm%SW;
    int hh = h + (rr-1)*R; int wg = w0 + ww - R;
    float v = 0.f;
    if ((unsigned)hh < (unsigned)Hs && (unsigned)wg < (unsigned)Wd_)
      v = xb[(size_t)c*HW + (size_t)hh*Wd_ + wg];
    xs[c][rr][ww] = v;
  }
  __syncthreads();

  const int p = threadIdx.x & 127;   // pixel in tile
  const int q = threadIdx.x >> 7;    // output-channel half (wave-uniform)
  float acc[OH];
  #pragma unroll
  for (int o=0;o<OH;o++) acc[o] = 0.f;

  for (int ki = 0; ki < 9; ki++){
    const int rr = ki/3, dxx = ki%3;
    float xv[Gc];
    #pragma unroll
    for (int c=0;c<Gc;c++) xv[c] = xs[c][rr][p + dxx*R];
    const int ob = q*OH;
    #pragma unroll
    for (int o=0;o<OH;o++){
      if (ob + o < OC){
        float a = acc[o];
        #pragma unroll
        for (int c=0;c<Gc;c++) a += w_s[ki][ob+o][c]*xv[c];
        acc[o] = a;
      }
    }
  }

  const int wpix = w0 + p;
  if (wpix < Wd_){
    float* ob_ = out + (size_t)b*OC*HW + (size_t)h*Wd_ + wpix;
    #pragma unroll
    for (int o=0;o<OH;o++){
      int oo = q*OH + o;
      if (oo < OC) ob_[(size_t)oo*HW] = acc[o] + b_s[oo];
    }
  }
}

// --------- deformable conv v3: chunked sample->FMA, prefetched offsets ----
// 1 px/thread; weights in LDS; channel chunks of 6 for MLP + low VGPR.
template<int R>
__global__ __launch_bounds__(256, 4) void k_deform3(
    const float* __restrict__ x, const float* __restrict__ off,
    const float* __restrict__ Wdf, const float* __restrict__ bd,
    float* __restrict__ out, int first)
{
  __shared__ float w_s[9][Gc][Gc];   // 32.4 KB
  __shared__ float b_s[Gc];
  for (int i = threadIdx.x; i < 9*Gc*Gc; i += 256){
    int ki = i/(Gc*Gc), rm = i%(Gc*Gc); int o = rm/Gc, c = rm%Gc;
    w_s[ki][o][c] = Wdf[(o*Gc + c)*9 + ki];
  }
  if (threadIdx.x < Gc) b_s[threadIdx.x] = bd[threadIdx.x];
  __syncthreads();

  const long idx = (long)blockIdx.x*256 + threadIdx.x;   // grid exact: no tail
  const int b = (int)(idx / HW); const int s = (int)(idx % HW);
  const int h = s / Wd_, w = s - h*Wd_;
  const float* xb  = x   + (size_t)b*Gc*HW;
  const float* ofb = off + (size_t)b*18*HW + s;

  // prefetch all 18 offsets into registers (removes per-tap load stalls)
  float oyv[9], oxv[9];
  #pragma unroll
  for (int ki=0; ki<9; ki++){
    oyv[ki] = ofb[(size_t)(2*ki)*HW];
    oxv[ki] = ofb[(size_t)(2*ki+1)*HW];
  }

  float acc[Gc];
  #pragma unroll
  for (int o=0;o<Gc;o++) acc[o] = 0.f;

  for (int ki = 0; ki < 9; ki++){
    Corners cr = mk_corners(oyv[ki] + (float)(h + (ki/3 - 1)*R),
                            oxv[ki] + (float)(w + (ki%3 - 1)*R));
    #pragma unroll
    for (int c0=0; c0<Gc; c0+=6){
      float sv[6];
      #pragma unroll
      for (int cc=0; cc<6; cc++){
        const float* xc = xb + (size_t)(c0+cc)*HW;
        sv[cc] = cr.m00*xc[cr.i00] + cr.m01*xc[cr.i01]
               + cr.m10*xc[cr.i10] + cr.m11*xc[cr.i11];
      }
      #pragma unroll
      for (int o=0;o<Gc;o++){
        float a = acc[o];
        #pragma unroll
        for (int cc=0; cc<6; cc++) a += w_s[ki][o][c0+cc]*sv[cc];
        acc[o] = a;
      }
    }
  }

  float* ob = out + (size_t)b*Gc*HW + s;
  if (first){
    #pragma unroll
    for (int o=0;o<Gc;o++) ob[(size_t)o*HW] = acc[o] + b_s[o];
  } else {
    #pragma unroll
    for (int o=0;o<Gc;o++) ob[(size_t)o*HW] += acc[o] + b_s[o];
  }
}

// ------- fused group_inner (1x1 matvec) + softmax gate, in-place on md ----
__global__ __launch_bounds__(256) void k_gate2(
    const float* __restrict__ x, const float* __restrict__ Wbl,
    const float* __restrict__ bbl, float* __restrict__ md)
{
  __shared__ float w_s[Gc][Gc];
  __shared__ float b_s[Gc];
  for (int i = threadIdx.x; i < Gc*Gc; i += 256)
    w_s[i/Gc][i%Gc] = Wbl[i];
  if (threadIdx.x < Gc) b_s[threadIdx.x] = bbl[threadIdx.x];
  __syncthreads();

  long idx = (long)blockIdx.x*256 + threadIdx.x;
  if (idx >= (long)BHW) return;
  int b = (int)(idx / HW); int s = (int)(idx % HW);
  const float* xp = x  + (size_t)b*Gc*HW + s;
  float*       mp = md + (size_t)b*Gc*HW + s;

  float xv[Gc];
  #pragma unroll
  for (int c=0;c<Gc;c++) xv[c] = xp[(size_t)c*HW];

  float gi[Gc];
  #pragma unroll
  for (int k=0;k<Gc;k++){
    float a = b_s[k];
    #pragma unroll
    for (int c=0;c<Gc;c++) a += w_s[k][c]*xv[c];
    gi[k] = a;
  }

  float v[Gc]; float mx = -1e30f;
  #pragma unroll
  for (int c=0;c<Gc;c++){ v[c] = mp[(size_t)c*HW]; mx = fmaxf(mx, v[c]); }
  float sum = 0.f;
  #pragma unroll
  for (int c=0;c<Gc;c++){ v[c] = __expf(v[c]-mx); sum += v[c]; }
  float inv = 1.f/sum;
  #pragma unroll
  for (int c=0;c<Gc;c++) mp[(size_t)c*HW] = gi[c] + gi[c]*(v[c]*inv);
}

// ---------------- projection GEMM: out[b,q,n] = W[q,p] F[b,p,n] + bias ----
__global__ __launch_bounds__(256) void k_proj(
    const float* __restrict__ F, const float* __restrict__ Wp,
    const float* __restrict__ bp, float* __restrict__ out)
{
  __shared__ float As[16][68];
  __shared__ float Bs[16][64];
  const int b = blockIdx.z;
  const int q0 = blockIdx.y*64;
  const int n0 = blockIdx.x*64;
  const int tid = threadIdx.x;
  const int tm = tid >> 4, tn = tid & 15;
  const int ar = tid >> 4, ac = tid & 15;
  const int br = tid >> 6, bc = tid & 63;
  const float* Fb = F + (size_t)b*PREN*Wd_;
  float acc[4][4] = {};
  for (int k0 = 0; k0 < PREN; k0 += 16){
    #pragma unroll
    for (int i=0;i<4;i++){
      int q = q0 + ar + 16*i;
      As[ac][ar + 16*i] = (q < PREN) ? Wp[(size_t)q*PREN + k0 + ac] : 0.f;
    }
    #pragma unroll
    for (int i=0;i<4;i++){
      int p = k0 + br + 4*i;
      int n = n0 + bc;
      Bs[br + 4*i][bc] = (n < Wd_) ? Fb[(size_t)p*Wd_ + n] : 0.f;
    }
    __syncthreads();
    #pragma unroll
    for (int k=0;k<16;k++){
      float4 a4 = *(const float4*)&As[k][tm*4];
      float4 b4 = *(const float4*)&Bs[k][tn*4];
      float av[4] = {a4.x,a4.y,a4.z,a4.w};
      float bv[4] = {b4.x,b4.y,b4.z,b4.w};
      #pragma unroll
      for (int i=0;i<4;i++)
        #pragma unroll
        for (int j=0;j<4;j++) acc[i][j] += av[i]*bv[j];
    }
    __syncthreads();
  }
  #pragma unroll
  for (int i=0;i<4;i++){
    int q = q0 + tm*4 + i;
    if (q >= PREN) continue;
    float bias = bp[q];
    #pragma unroll
    for (int j=0;j<4;j++){
      int n = n0 + tn*4 + j;
      if (n < Wd_) out[((size_t)b*PREN + q)*Wd_ + n] = acc[i][j] + bias;
    }
  }
}

extern "C" void kernel_launch(void* const* d_in, const int* in_sizes, int n_in,
                              void* d_out, int out_size, void* d_ws, size_t ws_size,
                              hipStream_t stream)
{
  (void)in_sizes; (void)n_in; (void)out_size; (void)ws_size;
  const float* x    = (const float*)d_in[0];
  const float* Wbl  = (const float*)d_in[1];
  const float* bbl  = (const float*)d_in[2];
  const float* Woff = (const float*)d_in[3];   // [2,18,30,3,3]
  const float* boff = (const float*)d_in[4];   // [2,18]
  const float* Wdef = (const float*)d_in[5];   // [2,30,30,3,3]
  const float* bdef = (const float*)d_in[6];   // [2,30]
  const float* Wff  = (const float*)d_in[7];   // [30,30,3,3]
  const float* bff  = (const float*)d_in[8];   // [30]
  const float* Wp   = (const float*)d_in[9];   // [720,720]
  const float* bp   = (const float*)d_in[10];  // [720]
  float* out = (float*)d_out;

  char* ws = (char*)d_ws;
  const size_t TEN = (size_t)BHW*Gc*sizeof(float);  // 39,720,960 B
  float* mdef = (float*)ws;          // [B,30,HW]; becomes repres in-place
  float* offb = (float*)(ws + TEN);  // [B,18,HW] (23.8 MB)
  float* Fbuf = (float*)(ws + TEN);  // ff output [B,30,HW]; offb dead by then

  const dim3 gconv((Wd_ + 127)/128, Hs, Bz);
  const int nblkPx = (BHW + 255)/256;   // 1293, exact

  // Multi_Def_Conv: rate 1 then rate 2 (accumulate)
  k_conv3x3s<18,1><<<gconv,256,0,stream>>>(x, Woff,        boff,      offb);
  k_deform3<1><<<nblkPx,256,0,stream>>>(x, offb, Wdef,        bdef,      mdef, 1);
  k_conv3x3s<18,2><<<gconv,256,0,stream>>>(x, Woff + 4860,  boff + 18, offb);
  k_deform3<2><<<nblkPx,256,0,stream>>>(x, offb, Wdef + 8100, bdef + 30, mdef, 0);

  // fused group_inner + softmax gate (in-place: mdef -> repres)
  k_gate2<<<nblkPx,256,0,stream>>>(x, Wbl, bbl, mdef);

  // ff 3x3 conv: repres -> Fbuf
  k_conv3x3s<30,1><<<gconv,256,0,stream>>>(mdef, Wff, bff, Fbuf);

  // projection GEMM
  dim3 gp((Wd_+63)/64, (PREN+63)/64, Bz);
  k_proj<<<gp,256,0,stream>>>(Fbuf, Wp, bp, out);
}

// Round 10
// 1719.343 us; speedup vs baseline: 3.4259x; 3.4259x over previous
//
#include <hip/hip_runtime.h>

// Problem constants
#define Bz 16
#define Gc 30
#define Hs 24
#define Wd_ 862
#define HW (Hs*Wd_)          // 20688
#define BHW (Bz*HW)          // 331008 = 1293 * 256 exactly
#define PREN 720

__device__ __forceinline__ int imin(int a,int b){return a<b?a:b;}
__device__ __forceinline__ int imax(int a,int b){return a>b?a:b;}

struct Corners { float m00,m01,m10,m11; int i00,i01,i10,i11; };

__device__ __forceinline__ Corners mk_corners(float py, float px){
  float y0f = floorf(py), x0f = floorf(px);
  float wy = py - y0f, wx = px - x0f;
  int y0 = (int)y0f, x0 = (int)x0f;
  int y1 = y0 + 1, x1 = x0 + 1;
  bool y0i = ((unsigned)y0 < (unsigned)Hs);
  bool y1i = ((unsigned)y1 < (unsigned)Hs);
  bool x0i = ((unsigned)x0 < (unsigned)Wd_);
  bool x1i = ((unsigned)x1 < (unsigned)Wd_);
  float w00=(1.f-wy)*(1.f-wx), w01=(1.f-wy)*wx, w10=wy*(1.f-wx), w11=wy*wx;
  Corners c;
  c.m00 = (y0i&&x0i)?w00:0.f; c.m01=(y0i&&x1i)?w01:0.f;
  c.m10 = (y1i&&x0i)?w10:0.f; c.m11=(y1i&&x1i)?w11:0.f;
  int y0c=imin(imax(y0,0),Hs-1), y1c=imin(imax(y1,0),Hs-1);
  int x0c=imin(imax(x0,0),Wd_-1), x1c=imin(imax(x1,0),Wd_-1);
  c.i00=y0c*Wd_+x0c; c.i01=y0c*Wd_+x1c; c.i10=y1c*Wd_+x0c; c.i11=y1c*Wd_+x1c;
  return c;
}

// ---- transpose x [b][c][h][w] -> xT [b][h][w][c=30] (channel-last) -------
__global__ __launch_bounds__(256) void k_transpose(
    const float* __restrict__ x, float* __restrict__ xT)
{
  __shared__ float xs[Gc][129];
  const int b = blockIdx.z, h = blockIdx.y, w0 = blockIdx.x*128;
  for (int i = threadIdx.x; i < Gc*128; i += 256){
    int c = i >> 7, ww = i & 127;
    int wg = w0 + ww;
    xs[c][ww] = (wg < Wd_) ? x[((size_t)b*Gc + c)*HW + (size_t)h*Wd_ + wg] : 0.f;
  }
  __syncthreads();
  const int ww = threadIdx.x;
  if (ww < 128 && w0 + ww < Wd_){
    float* dst = xT + ((size_t)(b*Hs + h)*Wd_ + w0 + ww)*(size_t)Gc;
    #pragma unroll
    for (int k=0;k<15;k++)
      ((float2*)dst)[k] = make_float2(xs[2*k][ww], xs[2*k+1][ww]);
  }
}

// ---------------- 3x3 conv, LDS row-staged. grid (7, Hs, Bz), block 256 ----
template<int OC, int R>
__global__ __launch_bounds__(256) void k_conv3x3s(
    const float* __restrict__ x, const float* __restrict__ Wo,
    const float* __restrict__ bo, float* __restrict__ out)
{
  constexpr int TILE = 128, SW = TILE + 2*R;
  constexpr int OH = (OC + 1) / 2;
  __shared__ float xs[Gc][3][SW];
  __shared__ float w_s[9][OC][Gc];
  __shared__ float b_s[OC];

  const int b = blockIdx.z, h = blockIdx.y, w0 = blockIdx.x * TILE;

  for (int i = threadIdx.x; i < 9*OC*Gc; i += 256){
    int ki = i/(OC*Gc), rm = i%(OC*Gc); int o = rm/Gc, c = rm%Gc;
    w_s[ki][o][c] = Wo[(o*Gc + c)*9 + ki];
  }
  if (threadIdx.x < OC) b_s[threadIdx.x] = bo[threadIdx.x];

  const float* xb = x + (size_t)b*Gc*HW;
  for (int i = threadIdx.x; i < Gc*3*SW; i += 256){
    int c = i/(3*SW), rm = i%(3*SW); int rr = rm/SW, ww = rm%SW;
    int hh = h + (rr-1)*R; int wg = w0 + ww - R;
    float v = 0.f;
    if ((unsigned)hh < (unsigned)Hs && (unsigned)wg < (unsigned)Wd_)
      v = xb[(size_t)c*HW + (size_t)hh*Wd_ + wg];
    xs[c][rr][ww] = v;
  }
  __syncthreads();

  const int p = threadIdx.x & 127;
  const int q = threadIdx.x >> 7;
  float acc[OH];
  #pragma unroll
  for (int o=0;o<OH;o++) acc[o] = 0.f;

  for (int ki = 0; ki < 9; ki++){
    const int rr = ki/3, dxx = ki%3;
    float xv[Gc];
    #pragma unroll
    for (int c=0;c<Gc;c++) xv[c] = xs[c][rr][p + dxx*R];
    const int ob = q*OH;
    #pragma unroll
    for (int o=0;o<OH;o++){
      if (ob + o < OC){
        float a = acc[o];
        #pragma unroll
        for (int c=0;c<Gc;c++) a += w_s[ki][ob+o][c]*xv[c];
        acc[o] = a;
      }
    }
  }

  const int wpix = w0 + p;
  if (wpix < Wd_){
    float* ob_ = out + (size_t)b*OC*HW + (size_t)h*Wd_ + wpix;
    #pragma unroll
    for (int o=0;o<OH;o++){
      int oo = q*OH + o;
      if (oo < OC) ob_[(size_t)oo*HW] = acc[o] + b_s[oo];
    }
  }
}

// ----- deformable conv v4: channel-last gathers (float2x15 per corner) ----
// 1 px/thread; weights in LDS; strided channel-major output (as deform2);
// bijective XCD swizzle for L2 locality. No forced occupancy (r7 lesson).
template<int R>
__global__ __launch_bounds__(256) void k_deform4(
    const float* __restrict__ xT, const float* __restrict__ off,
    const float* __restrict__ Wdf, const float* __restrict__ bd,
    float* __restrict__ out, int first)
{
  __shared__ float w_s[9][Gc][Gc];   // 32.4 KB
  __shared__ float b_s[Gc];
  for (int i = threadIdx.x; i < 9*Gc*Gc; i += 256){
    int ki = i/(Gc*Gc), rm = i%(Gc*Gc); int o = rm/Gc, c = rm%Gc;
    w_s[ki][o][c] = Wdf[(o*Gc + c)*9 + ki];
  }
  if (threadIdx.x < Gc) b_s[threadIdx.x] = bd[threadIdx.x];
  __syncthreads();

  // bijective XCD chunk swizzle (nb = 1293, not divisible by 8)
  const int nb = gridDim.x;
  const int qq = nb >> 3, rr8 = nb & 7;
  const int xcd = blockIdx.x & 7, lin = blockIdx.x >> 3;
  const int wgid = (xcd < rr8 ? xcd*(qq+1) : rr8*(qq+1) + (xcd-rr8)*qq) + lin;

  const long idx = (long)wgid*256 + threadIdx.x;   // grid exact: no tail
  const int b = (int)(idx / HW); const int s = (int)(idx % HW);
  const int h = s / Wd_, w = s - h*Wd_;
  const float* xTb = xT  + (size_t)b*HW*Gc;
  const float* ofb = off + (size_t)b*18*HW + s;

  float oyv[9], oxv[9];
  #pragma unroll
  for (int ki=0; ki<9; ki++){
    oyv[ki] = ofb[(size_t)(2*ki)*HW];
    oxv[ki] = ofb[(size_t)(2*ki+1)*HW];
  }

  float acc[Gc];
  #pragma unroll
  for (int o=0;o<Gc;o++) acc[o] = 0.f;

  for (int ki = 0; ki < 9; ki++){
    Corners cr = mk_corners(oyv[ki] + (float)(h + (ki/3 - 1)*R),
                            oxv[ki] + (float)(w + (ki%3 - 1)*R));
    const float2* p00 = (const float2*)(xTb + (size_t)cr.i00*Gc);
    const float2* p01 = (const float2*)(xTb + (size_t)cr.i01*Gc);
    const float2* p10 = (const float2*)(xTb + (size_t)cr.i10*Gc);
    const float2* p11 = (const float2*)(xTb + (size_t)cr.i11*Gc);
    float2 sv[15];
    #pragma unroll
    for (int k=0;k<15;k++){
      float2 a0 = p00[k], a1 = p01[k], a2 = p10[k], a3 = p11[k];
      sv[k].x = cr.m00*a0.x + cr.m01*a1.x + cr.m10*a2.x + cr.m11*a3.x;
      sv[k].y = cr.m00*a0.y + cr.m01*a1.y + cr.m10*a2.y + cr.m11*a3.y;
    }
    #pragma unroll
    for (int o=0;o<Gc;o++){
      float a = acc[o];
      #pragma unroll
      for (int k=0;k<15;k++){
        a += w_s[ki][o][2*k]   * sv[k].x;
        a += w_s[ki][o][2*k+1] * sv[k].y;
      }
      acc[o] = a;
    }
  }

  float* ob = out + (size_t)b*Gc*HW + s;
  if (first){
    #pragma unroll
    for (int o=0;o<Gc;o++) ob[(size_t)o*HW] = acc[o] + b_s[o];
  } else {
    #pragma unroll
    for (int o=0;o<Gc;o++) ob[(size_t)o*HW] += acc[o] + b_s[o];
  }
}

// ------- fused group_inner (1x1 matvec) + softmax gate, in-place on md ----
__global__ __launch_bounds__(256) void k_gate2(
    const float* __restrict__ x, const float* __restrict__ Wbl,
    const float* __restrict__ bbl, float* __restrict__ md)
{
  __shared__ float w_s[Gc][Gc];
  __shared__ float b_s[Gc];
  for (int i = threadIdx.x; i < Gc*Gc; i += 256)
    w_s[i/Gc][i%Gc] = Wbl[i];
  if (threadIdx.x < Gc) b_s[threadIdx.x] = bbl[threadIdx.x];
  __syncthreads();

  long idx = (long)blockIdx.x*256 + threadIdx.x;
  if (idx >= (long)BHW) return;
  int b = (int)(idx / HW); int s = (int)(idx % HW);
  const float* xp = x  + (size_t)b*Gc*HW + s;
  float*       mp = md + (size_t)b*Gc*HW + s;

  float xv[Gc];
  #pragma unroll
  for (int c=0;c<Gc;c++) xv[c] = xp[(size_t)c*HW];

  float gi[Gc];
  #pragma unroll
  for (int k=0;k<Gc;k++){
    float a = b_s[k];
    #pragma unroll
    for (int c=0;c<Gc;c++) a += w_s[k][c]*xv[c];
    gi[k] = a;
  }

  float v[Gc]; float mx = -1e30f;
  #pragma unroll
  for (int c=0;c<Gc;c++){ v[c] = mp[(size_t)c*HW]; mx = fmaxf(mx, v[c]); }
  float sum = 0.f;
  #pragma unroll
  for (int c=0;c<Gc;c++){ v[c] = __expf(v[c]-mx); sum += v[c]; }
  float inv = 1.f/sum;
  #pragma unroll
  for (int c=0;c<Gc;c++) mp[(size_t)c*HW] = gi[c] + gi[c]*(v[c]*inv);
}

// ---------------- projection GEMM: out[b,q,n] = W[q,p] F[b,p,n] + bias ----
__global__ __launch_bounds__(256) void k_proj(
    const float* __restrict__ F, const float* __restrict__ Wp,
    const float* __restrict__ bp, float* __restrict__ out)
{
  __shared__ float As[16][68];
  __shared__ float Bs[16][64];
  const int b = blockIdx.z;
  const int q0 = blockIdx.y*64;
  const int n0 = blockIdx.x*64;
  const int tid = threadIdx.x;
  const int tm = tid >> 4, tn = tid & 15;
  const int ar = tid >> 4, ac = tid & 15;
  const int br = tid >> 6, bc = tid & 63;
  const float* Fb = F + (size_t)b*PREN*Wd_;
  float acc[4][4] = {};
  for (int k0 = 0; k0 < PREN; k0 += 16){
    #pragma unroll
    for (int i=0;i<4;i++){
      int q = q0 + ar + 16*i;
      As[ac][ar + 16*i] = (q < PREN) ? Wp[(size_t)q*PREN + k0 + ac] : 0.f;
    }
    #pragma unroll
    for (int i=0;i<4;i++){
      int p = k0 + br + 4*i;
      int n = n0 + bc;
      Bs[br + 4*i][bc] = (n < Wd_) ? Fb[(size_t)p*Wd_ + n] : 0.f;
    }
    __syncthreads();
    #pragma unroll
    for (int k=0;k<16;k++){
      float4 a4 = *(const float4*)&As[k][tm*4];
      float4 b4 = *(const float4*)&Bs[k][tn*4];
      float av[4] = {a4.x,a4.y,a4.z,a4.w};
      float bv[4] = {b4.x,b4.y,b4.z,b4.w};
      #pragma unroll
      for (int i=0;i<4;i++)
        #pragma unroll
        for (int j=0;j<4;j++) acc[i][j] += av[i]*bv[j];
    }
    __syncthreads();
  }
  #pragma unroll
  for (int i=0;i<4;i++){
    int q = q0 + tm*4 + i;
    if (q >= PREN) continue;
    float bias = bp[q];
    #pragma unroll
    for (int j=0;j<4;j++){
      int n = n0 + tn*4 + j;
      if (n < Wd_) out[((size_t)b*PREN + q)*Wd_ + n] = acc[i][j] + bias;
    }
  }
}

extern "C" void kernel_launch(void* const* d_in, const int* in_sizes, int n_in,
                              void* d_out, int out_size, void* d_ws, size_t ws_size,
                              hipStream_t stream)
{
  (void)in_sizes; (void)n_in; (void)out_size; (void)ws_size;
  const float* x    = (const float*)d_in[0];
  const float* Wbl  = (const float*)d_in[1];
  const float* bbl  = (const float*)d_in[2];
  const float* Woff = (const float*)d_in[3];   // [2,18,30,3,3]
  const float* boff = (const float*)d_in[4];   // [2,18]
  const float* Wdef = (const float*)d_in[5];   // [2,30,30,3,3]
  const float* bdef = (const float*)d_in[6];   // [2,30]
  const float* Wff  = (const float*)d_in[7];   // [30,30,3,3]
  const float* bff  = (const float*)d_in[8];   // [30]
  const float* Wp   = (const float*)d_in[9];   // [720,720]
  const float* bp   = (const float*)d_in[10];  // [720]
  float* out = (float*)d_out;

  // Workspace: stay within the PROVEN 79.4 MB footprint (r8 lesson: the
  // 103 MB layout coincided with container death). offb (23.8 MB) lives in
  // d_out (39.7 MB f32) — legal scratch: only k_proj at the end writes the
  // real output, fully overwriting it; harness re-poisons d_out anyway.
  char* ws = (char*)d_ws;
  const size_t TEN = (size_t)BHW*Gc*sizeof(float);   // 39,720,960 B
  float* xT   = (float*)ws;                 // [B,H,W,30]; Fbuf aliases later
  float* mdef = (float*)(ws + TEN);         // [B,30,HW]; becomes repres
  float* offb = (float*)d_out;              // [B,18,HW] scratch in d_out
  float* Fbuf = xT;                         // ff output; xT dead by then

  const dim3 gconv((Wd_ + 127)/128, Hs, Bz);
  const int nblkPx = (BHW + 255)/256;   // 1293, exact

  // channel-last copy of x for the deform gathers
  k_transpose<<<gconv,256,0,stream>>>(x, xT);

  // Multi_Def_Conv: rate 1 then rate 2 (accumulate)
  k_conv3x3s<18,1><<<gconv,256,0,stream>>>(x, Woff,        boff,      offb);
  k_deform4<1><<<nblkPx,256,0,stream>>>(xT, offb, Wdef,        bdef,      mdef, 1);
  k_conv3x3s<18,2><<<gconv,256,0,stream>>>(x, Woff + 4860,  boff + 18, offb);
  k_deform4<2><<<nblkPx,256,0,stream>>>(xT, offb, Wdef + 8100, bdef + 30, mdef, 0);

  // fused group_inner + softmax gate (in-place: mdef -> repres)
  k_gate2<<<nblkPx,256,0,stream>>>(x, Wbl, bbl, mdef);

  // ff 3x3 conv: repres -> Fbuf (aliases xT, now dead)
  k_conv3x3s<30,1><<<gconv,256,0,stream>>>(mdef, Wff, bff, Fbuf);

  // projection GEMM (overwrites all of d_out, incl. the offb scratch)
  dim3 gp((Wd_+63)/64, (PREN+63)/64, Bz);
  k_proj<<<gp,256,0,stream>>>(Fbuf, Wp, bp, out);
}

// Round 11
// 1513.842 us; speedup vs baseline: 3.8910x; 1.1357x over previous
//
#include <hip/hip_runtime.h>

// Problem constants
#define Bz 16
#define Gc 30
#define Hs 24
#define Wd_ 862
#define HW (Hs*Wd_)          // 20688
#define BHW (Bz*HW)          // 331008 = 1293 * 256 exactly
#define PREN 720

__device__ __forceinline__ int imin(int a,int b){return a<b?a:b;}
__device__ __forceinline__ int imax(int a,int b){return a>b?a:b;}

struct Corners { float m00,m01,m10,m11; int i00,i01,i10,i11; };

__device__ __forceinline__ Corners mk_corners(float py, float px){
  float y0f = floorf(py), x0f = floorf(px);
  float wy = py - y0f, wx = px - x0f;
  int y0 = (int)y0f, x0 = (int)x0f;
  int y1 = y0 + 1, x1 = x0 + 1;
  bool y0i = ((unsigned)y0 < (unsigned)Hs);
  bool y1i = ((unsigned)y1 < (unsigned)Hs);
  bool x0i = ((unsigned)x0 < (unsigned)Wd_);
  bool x1i = ((unsigned)x1 < (unsigned)Wd_);
  float w00=(1.f-wy)*(1.f-wx), w01=(1.f-wy)*wx, w10=wy*(1.f-wx), w11=wy*wx;
  Corners c;
  c.m00 = (y0i&&x0i)?w00:0.f; c.m01=(y0i&&x1i)?w01:0.f;
  c.m10 = (y1i&&x0i)?w10:0.f; c.m11=(y1i&&x1i)?w11:0.f;
  int y0c=imin(imax(y0,0),Hs-1), y1c=imin(imax(y1,0),Hs-1);
  int x0c=imin(imax(x0,0),Wd_-1), x1c=imin(imax(x1,0),Wd_-1);
  c.i00=y0c*Wd_+x0c; c.i01=y0c*Wd_+x1c; c.i10=y1c*Wd_+x0c; c.i11=y1c*Wd_+x1c;
  return c;
}

// ---- weight repack into [ki][o][32] (c padded to 32) for scalar loads ----
// regions (floats): off r0 [0,5184) r1 [5184,10368); def r0 [10368,19008)
// r1 [19008,27648); ff [27648,36288)
#define WR_TOT 36288
__global__ __launch_bounds__(256) void k_repack(
    const float* __restrict__ Woff, const float* __restrict__ Wdef,
    const float* __restrict__ Wff, float* __restrict__ wr)
{
  int i = blockIdx.x*256 + threadIdx.x;
  if (i >= WR_TOT) return;
  float v;
  if (i < 10368){
    int r = i/5184, rm = i%5184;
    int ki = rm/576, rm2 = rm%576, o = rm2>>5, c = rm2&31;
    v = (c<Gc) ? Woff[r*4860 + (o*Gc+c)*9 + ki] : 0.f;
  } else if (i < 27648){
    int j = i-10368; int r = j/8640, rm = j%8640;
    int ki = rm/960, rm2 = rm%960, o = rm2>>5, c = rm2&31;
    v = (c<Gc) ? Wdef[r*8100 + (o*Gc+c)*9 + ki] : 0.f;
  } else {
    int j = i-27648; int ki = j/960, rm2 = j%960, o = rm2>>5, c = rm2&31;
    v = (c<Gc) ? Wff[(o*Gc+c)*9 + ki] : 0.f;
  }
  wr[i] = v;
}

// ---- transpose x [b][c][h][w] -> xT [b][h][w][c=30] (channel-last) -------
__global__ __launch_bounds__(256) void k_transpose(
    const float* __restrict__ x, float* __restrict__ xT)
{
  __shared__ float xs[Gc][129];
  const int b = blockIdx.z, h = blockIdx.y, w0 = blockIdx.x*128;
  for (int i = threadIdx.x; i < Gc*128; i += 256){
    int c = i >> 7, ww = i & 127;
    int wg = w0 + ww;
    xs[c][ww] = (wg < Wd_) ? x[((size_t)b*Gc + c)*HW + (size_t)h*Wd_ + wg] : 0.f;
  }
  __syncthreads();
  const int ww = threadIdx.x;
  if (ww < 128 && w0 + ww < Wd_){
    float* dst = xT + ((size_t)(b*Hs + h)*Wd_ + w0 + ww)*(size_t)Gc;
    #pragma unroll
    for (int k=0;k<15;k++)
      ((float2*)dst)[k] = make_float2(xs[2*k][ww], xs[2*k+1][ww]);
  }
}

// -------- 3x3 conv, LDS x-staging; weights via SGPR (scalar loads) --------
// grid (7, Hs, Bz), block 256 = 128 px x 2 output-channel halves.
template<int OC, int R>
__global__ __launch_bounds__(256) void k_conv3x3w(
    const float* __restrict__ x, const float* __restrict__ wrep, // [9][OC][32]
    const float* __restrict__ bo, float* __restrict__ out)
{
  constexpr int TILE = 128, SW = TILE + 2*R;
  constexpr int OH = OC / 2;           // OC in {18,30}: exact
  __shared__ float xs[Gc][3][SW];      // <= 47.5 KB (no weight LDS)

  const int b = blockIdx.z, h = blockIdx.y, w0 = blockIdx.x * TILE;

  const float* xb = x + (size_t)b*Gc*HW;
  for (int i = threadIdx.x; i < Gc*3*SW; i += 256){
    int c = i/(3*SW), rm = i%(3*SW); int rr = rm/SW, ww = rm%SW;
    int hh = h + (rr-1)*R; int wg = w0 + ww - R;
    float v = 0.f;
    if ((unsigned)hh < (unsigned)Hs && (unsigned)wg < (unsigned)Wd_)
      v = xb[(size_t)c*HW + (size_t)hh*Wd_ + wg];
    xs[c][rr][ww] = v;
  }
  __syncthreads();

  const int p = threadIdx.x & 127;                                  // pixel
  const int q = __builtin_amdgcn_readfirstlane(threadIdx.x >> 7);   // half, SGPR
  float acc[OH];
  #pragma unroll
  for (int o=0;o<OH;o++) acc[o] = 0.f;

  for (int ki = 0; ki < 9; ki++){
    const int rr = ki/3, dxx = ki%3;
    float xv[Gc];
    #pragma unroll
    for (int c=0;c<Gc;c++) xv[c] = xs[c][rr][p + dxx*R];
    const float* wk = wrep + (size_t)(ki*OC + q*OH)*32;  // uniform -> s_load
    #pragma unroll
    for (int o=0;o<OH;o++){
      float a = acc[o];
      #pragma unroll
      for (int c=0;c<Gc;c++) a += wk[o*32 + c]*xv[c];
      acc[o] = a;
    }
  }

  const int wpix = w0 + p;
  if (wpix < Wd_){
    float* ob_ = out + (size_t)b*OC*HW + (size_t)h*Wd_ + wpix;
    #pragma unroll
    for (int o=0;o<OH;o++){
      int oo = q*OH + o;
      ob_[(size_t)oo*HW] = acc[o] + bo[oo];
    }
  }
}

// ----- deformable conv v5: channel-last gathers + SGPR weights, NO LDS ----
template<int R>
__global__ __launch_bounds__(256) void k_deform5(
    const float* __restrict__ xT, const float* __restrict__ off,
    const float* __restrict__ wrep,   // [9][30][32]
    const float* __restrict__ bd,
    float* __restrict__ out, int first)
{
  // bijective XCD chunk swizzle (nb = 1293, not divisible by 8)
  const int nb = gridDim.x;
  const int qq = nb >> 3, rr8 = nb & 7;
  const int xcd = blockIdx.x & 7, lin = blockIdx.x >> 3;
  const int wgid = (xcd < rr8 ? xcd*(qq+1) : rr8*(qq+1) + (xcd-rr8)*qq) + lin;

  const long idx = (long)wgid*256 + threadIdx.x;   // grid exact: no tail
  const int b = (int)(idx / HW); const int s = (int)(idx % HW);
  const int h = s / Wd_, w = s - h*Wd_;
  const float* xTb = xT  + (size_t)b*HW*Gc;
  const float* ofb = off + (size_t)b*18*HW + s;

  float oyv[9], oxv[9];
  #pragma unroll
  for (int ki=0; ki<9; ki++){
    oyv[ki] = ofb[(size_t)(2*ki)*HW];
    oxv[ki] = ofb[(size_t)(2*ki+1)*HW];
  }

  float acc[Gc];
  #pragma unroll
  for (int o=0;o<Gc;o++) acc[o] = 0.f;

  for (int ki = 0; ki < 9; ki++){
    Corners cr = mk_corners(oyv[ki] + (float)(h + (ki/3 - 1)*R),
                            oxv[ki] + (float)(w + (ki%3 - 1)*R));
    const float2* p00 = (const float2*)(xTb + (size_t)cr.i00*Gc);
    const float2* p01 = (const float2*)(xTb + (size_t)cr.i01*Gc);
    const float2* p10 = (const float2*)(xTb + (size_t)cr.i10*Gc);
    const float2* p11 = (const float2*)(xTb + (size_t)cr.i11*Gc);
    float2 sv[15];
    #pragma unroll
    for (int k=0;k<15;k++){
      float2 a0 = p00[k], a1 = p01[k], a2 = p10[k], a3 = p11[k];
      sv[k].x = cr.m00*a0.x + cr.m01*a1.x + cr.m10*a2.x + cr.m11*a3.x;
      sv[k].y = cr.m00*a0.y + cr.m01*a1.y + cr.m10*a2.y + cr.m11*a3.y;
    }
    const float* wk = wrep + (size_t)ki*Gc*32;   // uniform -> s_load
    #pragma unroll
    for (int o=0;o<Gc;o++){
      float a = acc[o];
      #pragma unroll
      for (int k=0;k<15;k++){
        a += wk[o*32 + 2*k]   * sv[k].x;
        a += wk[o*32 + 2*k+1] * sv[k].y;
      }
      acc[o] = a;
    }
  }

  float* ob = out + (size_t)b*Gc*HW + s;
  if (first){
    #pragma unroll
    for (int o=0;o<Gc;o++) ob[(size_t)o*HW] = acc[o] + bd[o];
  } else {
    #pragma unroll
    for (int o=0;o<Gc;o++) ob[(size_t)o*HW] += acc[o] + bd[o];
  }
}

// --- fused group_inner (1x1 matvec, SGPR weights) + softmax gate ----------
__global__ __launch_bounds__(256) void k_gate3(
    const float* __restrict__ x, const float* __restrict__ Wbl,
    const float* __restrict__ bbl, float* __restrict__ md)
{
  long idx = (long)blockIdx.x*256 + threadIdx.x;
  if (idx >= (long)BHW) return;
  int b = (int)(idx / HW); int s = (int)(idx % HW);
  const float* xp = x  + (size_t)b*Gc*HW + s;
  float*       mp = md + (size_t)b*Gc*HW + s;

  float xv[Gc];
  #pragma unroll
  for (int c=0;c<Gc;c++) xv[c] = xp[(size_t)c*HW];

  float gi[Gc];
  #pragma unroll
  for (int k=0;k<Gc;k++){
    float a = bbl[k];                      // uniform -> s_load
    #pragma unroll
    for (int c=0;c<Gc;c++) a += Wbl[k*Gc + c]*xv[c];   // uniform -> s_load
    gi[k] = a;
  }

  float v[Gc]; float mx = -1e30f;
  #pragma unroll
  for (int c=0;c<Gc;c++){ v[c] = mp[(size_t)c*HW]; mx = fmaxf(mx, v[c]); }
  float sum = 0.f;
  #pragma unroll
  for (int c=0;c<Gc;c++){ v[c] = __expf(v[c]-mx); sum += v[c]; }
  float inv = 1.f/sum;
  #pragma unroll
  for (int c=0;c<Gc;c++) mp[(size_t)c*HW] = gi[c] + gi[c]*(v[c]*inv);
}

// ---------------- projection GEMM: out[b,q,n] = W[q,p] F[b,p,n] + bias ----
__global__ __launch_bounds__(256) void k_proj(
    const float* __restrict__ F, const float* __restrict__ Wp,
    const float* __restrict__ bp, float* __restrict__ out)
{
  __shared__ float As[16][68];
  __shared__ float Bs[16][64];
  const int b = blockIdx.z;
  const int q0 = blockIdx.y*64;
  const int n0 = blockIdx.x*64;
  const int tid = threadIdx.x;
  const int tm = tid >> 4, tn = tid & 15;
  const int ar = tid >> 4, ac = tid & 15;
  const int br = tid >> 6, bc = tid & 63;
  const float* Fb = F + (size_t)b*PREN*Wd_;
  float acc[4][4] = {};
  for (int k0 = 0; k0 < PREN; k0 += 16){
    #pragma unroll
    for (int i=0;i<4;i++){
      int q = q0 + ar + 16*i;
      As[ac][ar + 16*i] = (q < PREN) ? Wp[(size_t)q*PREN + k0 + ac] : 0.f;
    }
    #pragma unroll
    for (int i=0;i<4;i++){
      int p = k0 + br + 4*i;
      int n = n0 + bc;
      Bs[br + 4*i][bc] = (n < Wd_) ? Fb[(size_t)p*Wd_ + n] : 0.f;
    }
    __syncthreads();
    #pragma unroll
    for (int k=0;k<16;k++){
      float4 a4 = *(const float4*)&As[k][tm*4];
      float4 b4 = *(const float4*)&Bs[k][tn*4];
      float av[4] = {a4.x,a4.y,a4.z,a4.w};
      float bv[4] = {b4.x,b4.y,b4.z,b4.w};
      #pragma unroll
      for (int i=0;i<4;i++)
        #pragma unroll
        for (int j=0;j<4;j++) acc[i][j] += av[i]*bv[j];
    }
    __syncthreads();
  }
  #pragma unroll
  for (int i=0;i<4;i++){
    int q = q0 + tm*4 + i;
    if (q >= PREN) continue;
    float bias = bp[q];
    #pragma unroll
    for (int j=0;j<4;j++){
      int n = n0 + tn*4 + j;
      if (n < Wd_) out[((size_t)b*PREN + q)*Wd_ + n] = acc[i][j] + bias;
    }
  }
}

extern "C" void kernel_launch(void* const* d_in, const int* in_sizes, int n_in,
                              void* d_out, int out_size, void* d_ws, size_t ws_size,
                              hipStream_t stream)
{
  (void)in_sizes; (void)n_in; (void)out_size; (void)ws_size;
  const float* x    = (const float*)d_in[0];
  const float* Wbl  = (const float*)d_in[1];
  const float* bbl  = (const float*)d_in[2];
  const float* Woff = (const float*)d_in[3];   // [2,18,30,3,3]
  const float* boff = (const float*)d_in[4];   // [2,18]
  const float* Wdef = (const float*)d_in[5];   // [2,30,30,3,3]
  const float* bdef = (const float*)d_in[6];   // [2,30]
  const float* Wff  = (const float*)d_in[7];   // [30,30,3,3]
  const float* bff  = (const float*)d_in[8];   // [30]
  const float* Wp   = (const float*)d_in[9];   // [720,720]
  const float* bp   = (const float*)d_in[10];  // [720]
  float* out = (float*)d_out;

  // Workspace: proven 79.4 MB footprint in d_ws. d_out doubles as scratch:
  //   offb  = d_out[0 .. 23.8 MB)   (offsets, dead before k_proj)
  //   wrep  = d_out[32 MB .. 32.14 MB) (repacked weights, dead before k_proj)
  // k_proj fully overwrites d_out at the end.
  char* ws = (char*)d_ws;
  const size_t TEN = (size_t)BHW*Gc*sizeof(float);   // 39,720,960 B
  float* xT   = (float*)ws;                 // [B,H,W,30]; Fbuf aliases later
  float* mdef = (float*)(ws + TEN);         // [B,30,HW]; becomes repres
  float* offb = (float*)d_out;              // [B,18,HW] scratch in d_out
  float* wrep = (float*)((char*)d_out + (32u<<20));  // 145 KB scratch
  float* Fbuf = xT;                         // ff output; xT dead by then

  const float* wr_off0 = wrep;              // [9][18][32]
  const float* wr_off1 = wrep + 5184;
  const float* wr_def0 = wrep + 10368;      // [9][30][32]
  const float* wr_def1 = wrep + 19008;
  const float* wr_ff   = wrep + 27648;      // [9][30][32]

  const dim3 gconv((Wd_ + 127)/128, Hs, Bz);
  const int nblkPx = (BHW + 255)/256;   // 1293, exact

  // repack weights + channel-last copy of x
  k_repack<<<(WR_TOT+255)/256,256,0,stream>>>(Woff, Wdef, Wff, wrep);
  k_transpose<<<gconv,256,0,stream>>>(x, xT);

  // Multi_Def_Conv: rate 1 then rate 2 (accumulate)
  k_conv3x3w<18,1><<<gconv,256,0,stream>>>(x, wr_off0, boff,      offb);
  k_deform5<1><<<nblkPx,256,0,stream>>>(xT, offb, wr_def0, bdef,      mdef, 1);
  k_conv3x3w<18,2><<<gconv,256,0,stream>>>(x, wr_off1, boff + 18, offb);
  k_deform5<2><<<nblkPx,256,0,stream>>>(xT, offb, wr_def1, bdef + 30, mdef, 0);

  // fused group_inner + softmax gate (in-place: mdef -> repres)
  k_gate3<<<nblkPx,256,0,stream>>>(x, Wbl, bbl, mdef);

  // ff 3x3 conv: repres -> Fbuf (aliases xT, now dead)
  k_conv3x3w<30,1><<<gconv,256,0,stream>>>(mdef, wr_ff, bff, Fbuf);

  // projection GEMM (overwrites all of d_out, incl. scratch regions)
  dim3 gp((Wd_+63)/64, (PREN+63)/64, Bz);
  k_proj<<<gp,256,0,stream>>>(Fbuf, Wp, bp, out);
}

// Round 12
// 1352.443 us; speedup vs baseline: 4.3554x; 1.1193x over previous
//
#include <hip/hip_runtime.h>
#include <hip/hip_bf16.h>

// Problem constants
#define Bz 16
#define Gc 30
#define Hs 24
#define Wd_ 862
#define HW (Hs*Wd_)          // 20688
#define BHW (Bz*HW)          // 331008 = 1293 * 256 exactly
#define PREN 720

typedef __attribute__((ext_vector_type(8))) short bf16x8;
typedef __attribute__((ext_vector_type(4))) float f32x4;

__device__ __forceinline__ int imin(int a,int b){return a<b?a:b;}
__device__ __forceinline__ int imax(int a,int b){return a>b?a:b;}

__device__ __forceinline__ unsigned short f2bf(float f){
  __hip_bfloat16 h = __float2bfloat16(f);
  return *reinterpret_cast<unsigned short*>(&h);
}

struct Corners { float m00,m01,m10,m11; int i00,i01,i10,i11; };

__device__ __forceinline__ Corners mk_corners(float py, float px){
  float y0f = floorf(py), x0f = floorf(px);
  float wy = py - y0f, wx = px - x0f;
  int y0 = (int)y0f, x0 = (int)x0f;
  int y1 = y0 + 1, x1 = x0 + 1;
  bool y0i = ((unsigned)y0 < (unsigned)Hs);
  bool y1i = ((unsigned)y1 < (unsigned)Hs);
  bool x0i = ((unsigned)x0 < (unsigned)Wd_);
  bool x1i = ((unsigned)x1 < (unsigned)Wd_);
  float w00=(1.f-wy)*(1.f-wx), w01=(1.f-wy)*wx, w10=wy*(1.f-wx), w11=wy*wx;
  Corners c;
  c.m00 = (y0i&&x0i)?w00:0.f; c.m01=(y0i&&x1i)?w01:0.f;
  c.m10 = (y1i&&x0i)?w10:0.f; c.m11=(y1i&&x1i)?w11:0.f;
  int y0c=imin(imax(y0,0),Hs-1), y1c=imin(imax(y1,0),Hs-1);
  int x0c=imin(imax(x0,0),Wd_-1), x1c=imin(imax(x1,0),Wd_-1);
  c.i00=y0c*Wd_+x0c; c.i01=y0c*Wd_+x1c; c.i10=y1c*Wd_+x0c; c.i11=y1c*Wd_+x1c;
  return c;
}

// ---- weight repack into [ki][o][32] (c padded to 32) for scalar loads ----
#define WR_TOT 36288
__global__ __launch_bounds__(256) void k_repack(
    const float* __restrict__ Woff, const float* __restrict__ Wdef,
    const float* __restrict__ Wff, float* __restrict__ wr)
{
  int i = blockIdx.x*256 + threadIdx.x;
  if (i >= WR_TOT) return;
  float v;
  if (i < 10368){
    int r = i/5184, rm = i%5184;
    int ki = rm/576, rm2 = rm%576, o = rm2>>5, c = rm2&31;
    v = (c<Gc) ? Woff[r*4860 + (o*Gc+c)*9 + ki] : 0.f;
  } else if (i < 27648){
    int j = i-10368; int r = j/8640, rm = j%8640;
    int ki = rm/960, rm2 = rm%960, o = rm2>>5, c = rm2&31;
    v = (c<Gc) ? Wdef[r*8100 + (o*Gc+c)*9 + ki] : 0.f;
  } else {
    int j = i-27648; int ki = j/960, rm2 = j%960, o = rm2>>5, c = rm2&31;
    v = (c<Gc) ? Wff[(o*Gc+c)*9 + ki] : 0.f;
  }
  wr[i] = v;
}

// ---- transpose x [b][c][h][w] -> xT [b][h][w][c=30] (channel-last) -------
__global__ __launch_bounds__(256) void k_transpose(
    const float* __restrict__ x, float* __restrict__ xT)
{
  __shared__ float xs[Gc][129];
  const int b = blockIdx.z, h = blockIdx.y, w0 = blockIdx.x*128;
  for (int i = threadIdx.x; i < Gc*128; i += 256){
    int c = i >> 7, ww = i & 127;
    int wg = w0 + ww;
    xs[c][ww] = (wg < Wd_) ? x[((size_t)b*Gc + c)*HW + (size_t)h*Wd_ + wg] : 0.f;
  }
  __syncthreads();
  const int ww = threadIdx.x;
  if (ww < 128 && w0 + ww < Wd_){
    float* dst = xT + ((size_t)(b*Hs + h)*Wd_ + w0 + ww)*(size_t)Gc;
    #pragma unroll
    for (int k=0;k<15;k++)
      ((float2*)dst)[k] = make_float2(xs[2*k][ww], xs[2*k+1][ww]);
  }
}

// -------- 3x3 conv, LDS x-staging; weights via SGPR (scalar loads) --------
template<int OC, int R>
__global__ __launch_bounds__(256) void k_conv3x3w(
    const float* __restrict__ x, const float* __restrict__ wrep, // [9][OC][32]
    const float* __restrict__ bo, float* __restrict__ out)
{
  constexpr int TILE = 128, SW = TILE + 2*R;
  constexpr int OH = OC / 2;
  __shared__ float xs[Gc][3][SW];

  const int b = blockIdx.z, h = blockIdx.y, w0 = blockIdx.x * TILE;

  const float* xb = x + (size_t)b*Gc*HW;
  for (int i = threadIdx.x; i < Gc*3*SW; i += 256){
    int c = i/(3*SW), rm = i%(3*SW); int rr = rm/SW, ww = rm%SW;
    int hh = h + (rr-1)*R; int wg = w0 + ww - R;
    float v = 0.f;
    if ((unsigned)hh < (unsigned)Hs && (unsigned)wg < (unsigned)Wd_)
      v = xb[(size_t)c*HW + (size_t)hh*Wd_ + wg];
    xs[c][rr][ww] = v;
  }
  __syncthreads();

  const int p = threadIdx.x & 127;
  const int q = __builtin_amdgcn_readfirstlane(threadIdx.x >> 7);
  float acc[OH];
  #pragma unroll
  for (int o=0;o<OH;o++) acc[o] = 0.f;

  for (int ki = 0; ki < 9; ki++){
    const int rr = ki/3, dxx = ki%3;
    float xv[Gc];
    #pragma unroll
    for (int c=0;c<Gc;c++) xv[c] = xs[c][rr][p + dxx*R];
    const float* wk = wrep + (size_t)(ki*OC + q*OH)*32;  // uniform -> s_load
    #pragma unroll
    for (int o=0;o<OH;o++){
      float a = acc[o];
      #pragma unroll
      for (int c=0;c<Gc;c++) a += wk[o*32 + c]*xv[c];
      acc[o] = a;
    }
  }

  const int wpix = w0 + p;
  if (wpix < Wd_){
    float* ob_ = out + (size_t)b*OC*HW + (size_t)h*Wd_ + wpix;
    #pragma unroll
    for (int o=0;o<OH;o++){
      int oo = q*OH + o;
      ob_[(size_t)oo*HW] = acc[o] + bo[oo];
    }
  }
}

// ----- deformable conv v5: channel-last gathers + SGPR weights, NO LDS ----
template<int R>
__global__ __launch_bounds__(256) void k_deform5(
    const float* __restrict__ xT, const float* __restrict__ off,
    const float* __restrict__ wrep,   // [9][30][32]
    const float* __restrict__ bd,
    float* __restrict__ out, int first)
{
  const int nb = gridDim.x;
  const int qq = nb >> 3, rr8 = nb & 7;
  const int xcd = blockIdx.x & 7, lin = blockIdx.x >> 3;
  const int wgid = (xcd < rr8 ? xcd*(qq+1) : rr8*(qq+1) + (xcd-rr8)*qq) + lin;

  const long idx = (long)wgid*256 + threadIdx.x;
  const int b = (int)(idx / HW); const int s = (int)(idx % HW);
  const int h = s / Wd_, w = s - h*Wd_;
  const float* xTb = xT  + (size_t)b*HW*Gc;
  const float* ofb = off + (size_t)b*18*HW + s;

  float oyv[9], oxv[9];
  #pragma unroll
  for (int ki=0; ki<9; ki++){
    oyv[ki] = ofb[(size_t)(2*ki)*HW];
    oxv[ki] = ofb[(size_t)(2*ki+1)*HW];
  }

  float acc[Gc];
  #pragma unroll
  for (int o=0;o<Gc;o++) acc[o] = 0.f;

  for (int ki = 0; ki < 9; ki++){
    Corners cr = mk_corners(oyv[ki] + (float)(h + (ki/3 - 1)*R),
                            oxv[ki] + (float)(w + (ki%3 - 1)*R));
    const float2* p00 = (const float2*)(xTb + (size_t)cr.i00*Gc);
    const float2* p01 = (const float2*)(xTb + (size_t)cr.i01*Gc);
    const float2* p10 = (const float2*)(xTb + (size_t)cr.i10*Gc);
    const float2* p11 = (const float2*)(xTb + (size_t)cr.i11*Gc);
    float2 sv[15];
    #pragma unroll
    for (int k=0;k<15;k++){
      float2 a0 = p00[k], a1 = p01[k], a2 = p10[k], a3 = p11[k];
      sv[k].x = cr.m00*a0.x + cr.m01*a1.x + cr.m10*a2.x + cr.m11*a3.x;
      sv[k].y = cr.m00*a0.y + cr.m01*a1.y + cr.m10*a2.y + cr.m11*a3.y;
    }
    const float* wk = wrep + (size_t)ki*Gc*32;   // uniform -> s_load
    #pragma unroll
    for (int o=0;o<Gc;o++){
      float a = acc[o];
      #pragma unroll
      for (int k=0;k<15;k++){
        a += wk[o*32 + 2*k]   * sv[k].x;
        a += wk[o*32 + 2*k+1] * sv[k].y;
      }
      acc[o] = a;
    }
  }

  float* ob = out + (size_t)b*Gc*HW + s;
  if (first){
    #pragma unroll
    for (int o=0;o<Gc;o++) ob[(size_t)o*HW] = acc[o] + bd[o];
  } else {
    #pragma unroll
    for (int o=0;o<Gc;o++) ob[(size_t)o*HW] += acc[o] + bd[o];
  }
}

// --- fused group_inner (1x1 matvec, SGPR weights) + softmax gate ----------
__global__ __launch_bounds__(256) void k_gate3(
    const float* __restrict__ x, const float* __restrict__ Wbl,
    const float* __restrict__ bbl, float* __restrict__ md)
{
  long idx = (long)blockIdx.x*256 + threadIdx.x;
  if (idx >= (long)BHW) return;
  int b = (int)(idx / HW); int s = (int)(idx % HW);
  const float* xp = x  + (size_t)b*Gc*HW + s;
  float*       mp = md + (size_t)b*Gc*HW + s;

  float xv[Gc];
  #pragma unroll
  for (int c=0;c<Gc;c++) xv[c] = xp[(size_t)c*HW];

  float gi[Gc];
  #pragma unroll
  for (int k=0;k<Gc;k++){
    float a = bbl[k];
    #pragma unroll
    for (int c=0;c<Gc;c++) a += Wbl[k*Gc + c]*xv[c];
    gi[k] = a;
  }

  float v[Gc]; float mx = -1e30f;
  #pragma unroll
  for (int c=0;c<Gc;c++){ v[c] = mp[(size_t)c*HW]; mx = fmaxf(mx, v[c]); }
  float sum = 0.f;
  #pragma unroll
  for (int c=0;c<Gc;c++){ v[c] = __expf(v[c]-mx); sum += v[c]; }
  float inv = 1.f/sum;
  #pragma unroll
  for (int c=0;c<Gc;c++) mp[(size_t)c*HW] = gi[c] + gi[c]*(v[c]*inv);
}

// ---- convert Wp (f32 [720][720]) -> bf16 row-major -----------------------
__global__ __launch_bounds__(256) void k_cvt_w(
    const float* __restrict__ Wp, unsigned short* __restrict__ Wbf)
{
  int i = blockIdx.x*256 + threadIdx.x;
  if (i < PREN*PREN) Wbf[i] = f2bf(Wp[i]);
}

// ---- convert+transpose F (f32 [b][720][862]) -> bf16 [b][862][720] -------
// grid (14, 15, Bz): tile P=48 x N=64
__global__ __launch_bounds__(256) void k_cvtT(
    const float* __restrict__ F, unsigned short* __restrict__ Ft)
{
  __shared__ float xs[48][65];
  const int b = blockIdx.z, p0 = blockIdx.y*48, n0 = blockIdx.x*64;
  const float* Fb = F + (size_t)b*PREN*Wd_;
  #pragma unroll
  for (int t=0;t<12;t++){
    int idx = t*256 + threadIdx.x;
    int pr = idx >> 6, nc = idx & 63;
    xs[pr][nc] = (n0+nc < Wd_) ? Fb[(size_t)(p0+pr)*Wd_ + n0+nc] : 0.f;
  }
  __syncthreads();
  unsigned short* Tb = Ft + (size_t)b*Wd_*PREN;
  #pragma unroll
  for (int t=0;t<6;t++){
    int idx = t*256 + threadIdx.x;
    int row = idx/24, cu = idx - row*24;
    if (n0+row < Wd_){
      unsigned int lo = f2bf(xs[cu*2][row]);
      unsigned int hi = f2bf(xs[cu*2+1][row]);
      ((unsigned int*)(Tb + (size_t)(n0+row)*PREN + p0))[cu] = lo | (hi<<16);
    }
  }
}

// ---- projection GEMM via MFMA bf16: out[b,q,n] = W[q,p] F[b,p,n] + bias --
// grid (ceil(862/64)=14, 720/48=15, Bz); block 256 = 4 waves.
// Wave wv owns cols [wv*16, wv*16+16); 3 row-tiles of 16 -> 48 rows/block.
// Frag maps: A row=lane&15, k=(lane>>4)*8+i; B col=lane&15, same k;
// D col=lane&15, row=(lane>>4)*4+reg  [m89-verified].
__global__ __launch_bounds__(256) void k_projm(
    const unsigned short* __restrict__ Wbf,   // [720][720] bf16
    const unsigned short* __restrict__ Fbt,   // [b][862][720] bf16
    const float* __restrict__ bp, float* __restrict__ out)
{
  __shared__ unsigned short As[48*40];   // rows padded to 40 (80 B = 5x16B)
  __shared__ unsigned short Bs[64*40];
  const int b = blockIdx.z, q0 = blockIdx.y*48, n0 = blockIdx.x*64;
  const int tid = threadIdx.x;
  const int lane = tid & 63, wv = tid >> 6;
  const unsigned short* Fb = Fbt + (size_t)b*Wd_*PREN;

  f32x4 acc[3];
  #pragma unroll
  for (int rt=0;rt<3;rt++)
    #pragma unroll
    for (int i=0;i<4;i++) acc[rt][i] = 0.f;

  for (int k0 = 0; k0 < PREN; k0 += 32){
    #pragma unroll
    for (int t=0;t<3;t++){          // A-tile: 48 rows x 16 uints
      int idx = t*256 + tid; int row = idx >> 4, cu = idx & 15;
      unsigned int v = 0;
      if (k0 + cu*2 < PREN)
        v = *(const unsigned int*)(Wbf + (size_t)(q0+row)*PREN + k0 + cu*2);
      ((unsigned int*)As)[row*20 + cu] = v;
    }
    #pragma unroll
    for (int t=0;t<4;t++){          // B-tile: 64 rows(n) x 16 uints(k)
      int idx = t*256 + tid; int row = idx >> 4, cu = idx & 15;
      unsigned int v = 0;
      if ((n0+row) < Wd_ && k0 + cu*2 < PREN)
        v = *(const unsigned int*)(Fb + (size_t)(n0+row)*PREN + k0 + cu*2);
      ((unsigned int*)Bs)[row*20 + cu] = v;
    }
    __syncthreads();
    bf16x8 bfr = *(const bf16x8*)(Bs + (size_t)(wv*16 + (lane&15))*40 + (lane>>4)*8);
    #pragma unroll
    for (int rt=0;rt<3;rt++){
      bf16x8 afr = *(const bf16x8*)(As + (size_t)(rt*16 + (lane&15))*40 + (lane>>4)*8);
      acc[rt] = __builtin_amdgcn_mfma_f32_16x16x32_bf16(afr, bfr, acc[rt], 0, 0, 0);
    }
    __syncthreads();
  }

  const int n = n0 + wv*16 + (lane&15);
  if (n < Wd_){
    #pragma unroll
    for (int rt=0;rt<3;rt++){
      #pragma unroll
      for (int i=0;i<4;i++){
        int q = q0 + rt*16 + (lane>>4)*4 + i;
        out[((size_t)b*PREN + q)*Wd_ + n] = acc[rt][i] + bp[q];
      }
    }
  }
}

extern "C" void kernel_launch(void* const* d_in, const int* in_sizes, int n_in,
                              void* d_out, int out_size, void* d_ws, size_t ws_size,
                              hipStream_t stream)
{
  (void)in_sizes; (void)n_in; (void)out_size; (void)ws_size;
  const float* x    = (const float*)d_in[0];
  const float* Wbl  = (const float*)d_in[1];
  const float* bbl  = (const float*)d_in[2];
  const float* Woff = (const float*)d_in[3];   // [2,18,30,3,3]
  const float* boff = (const float*)d_in[4];   // [2,18]
  const float* Wdef = (const float*)d_in[5];   // [2,30,30,3,3]
  const float* bdef = (const float*)d_in[6];   // [2,30]
  const float* Wff  = (const float*)d_in[7];   // [30,30,3,3]
  const float* bff  = (const float*)d_in[8];   // [30]
  const float* Wp   = (const float*)d_in[9];   // [720,720]
  const float* bp   = (const float*)d_in[10];  // [720]
  float* out = (float*)d_out;

  // d_ws (79.4 MB proven): xT [0,39.7) — later Fbuf; mdef [39.7,79.4) —
  // after conv30 this region is dead and reused for Wbf + Fbf_t (bf16).
  // d_out scratch: offb [0,23.8), wrep [32 MB, +145 KB) — both dead before
  // k_projm overwrites d_out with the real output.
  char* ws = (char*)d_ws;
  const size_t TEN = (size_t)BHW*Gc*sizeof(float);   // 39,720,960 B
  float* xT   = (float*)ws;
  float* mdef = (float*)(ws + TEN);
  float* offb = (float*)d_out;
  float* wrep = (float*)((char*)d_out + (32u<<20));
  float* Fbuf = xT;
  unsigned short* Wbf  = (unsigned short*)(ws + TEN);              // 1.04 MB
  unsigned short* Fbft = (unsigned short*)(ws + TEN + (1u<<20)*2); // 19.9 MB

  const float* wr_off0 = wrep;              // [9][18][32]
  const float* wr_off1 = wrep + 5184;
  const float* wr_def0 = wrep + 10368;      // [9][30][32]
  const float* wr_def1 = wrep + 19008;
  const float* wr_ff   = wrep + 27648;      // [9][30][32]

  const dim3 gconv((Wd_ + 127)/128, Hs, Bz);
  const int nblkPx = (BHW + 255)/256;   // 1293, exact

  // repack weights + channel-last copy of x
  k_repack<<<(WR_TOT+255)/256,256,0,stream>>>(Woff, Wdef, Wff, wrep);
  k_transpose<<<gconv,256,0,stream>>>(x, xT);

  // Multi_Def_Conv: rate 1 then rate 2 (accumulate)
  k_conv3x3w<18,1><<<gconv,256,0,stream>>>(x, wr_off0, boff,      offb);
  k_deform5<1><<<nblkPx,256,0,stream>>>(xT, offb, wr_def0, bdef,      mdef, 1);
  k_conv3x3w<18,2><<<gconv,256,0,stream>>>(x, wr_off1, boff + 18, offb);
  k_deform5<2><<<nblkPx,256,0,stream>>>(xT, offb, wr_def1, bdef + 30, mdef, 0);

  // fused group_inner + softmax gate (in-place: mdef -> repres)
  k_gate3<<<nblkPx,256,0,stream>>>(x, Wbl, bbl, mdef);

  // ff 3x3 conv: repres -> Fbuf (aliases xT)
  k_conv3x3w<30,1><<<gconv,256,0,stream>>>(mdef, wr_ff, bff, Fbuf);

  // bf16 conversions (mdef region now dead): Wp -> Wbf, Fbuf -> Fbf_t
  k_cvt_w<<<(PREN*PREN+255)/256,256,0,stream>>>(Wp, Wbf);
  dim3 gcv((Wd_+63)/64, PREN/48, Bz);
  k_cvtT<<<gcv,256,0,stream>>>(Fbuf, Fbft);

  // projection GEMM via MFMA (overwrites all of d_out, incl. scratch)
  dim3 gp((Wd_+63)/64, PREN/48, Bz);
  k_projm<<<gp,256,0,stream>>>(Wbf, Fbft, bp, out);
}